// Round 1
// baseline (848.825 us; speedup 1.0000x reference)
//
#include <hip/hip_runtime.h>

#define N_NODES 100000
#define N_EDGES 1600000
#define D_IN 128
#define D_HID 64
#define BN_EPS 1e-5f

// --- degree count: one thread per edge, atomic count into deg[col] ---
__global__ __launch_bounds__(256) void deg_kernel(const int* __restrict__ col,
                                                  float* __restrict__ deg) {
    int e = blockIdx.x * 256 + threadIdx.x;
    if (e < N_EDGES) atomicAdd(&deg[col[e]], 1.0f);
}

// --- dinv = rsqrt(deg + 1)  (self-loop makes deg >= 1) ---
__global__ __launch_bounds__(256) void dinv_kernel(float* __restrict__ deg) {
    int n = blockIdx.x * 256 + threadIdx.x;
    if (n < N_NODES) deg[n] = rsqrtf(deg[n] + 1.0f);
}

// --- h_lin = x @ W1 : 16 nodes per block, W1 + x-tile in LDS ---
__global__ __launch_bounds__(256) void gemm_kernel(const float* __restrict__ x,
                                                   const float* __restrict__ W,
                                                   float* __restrict__ h) {
    __shared__ float ws[D_IN * D_HID];   // 32 KB
    __shared__ float xs[16][D_IN];       // 8 KB
    const int t = threadIdx.x;
    for (int i = t; i < D_IN * D_HID; i += 256) ws[i] = W[i];
    const int node0 = blockIdx.x * 16;
    for (int i = t; i < 16 * D_IN; i += 256) {
        int nl = i >> 7, k = i & 127;
        xs[nl][k] = x[(node0 + nl) * D_IN + k];
    }
    __syncthreads();
    const int d = t & 63;        // feature
    const int nl0 = t >> 6;      // 0..3 (wave-uniform)
    float acc0 = 0.f, acc1 = 0.f, acc2 = 0.f, acc3 = 0.f;
    for (int k = 0; k < D_IN; ++k) {
        float w = ws[k * D_HID + d];       // 2 lanes/bank: free
        acc0 += xs[nl0][k] * w;            // broadcast within wave
        acc1 += xs[nl0 + 4][k] * w;
        acc2 += xs[nl0 + 8][k] * w;
        acc3 += xs[nl0 + 12][k] * w;
    }
    h[(node0 + nl0) * D_HID + d] = acc0;
    h[(node0 + nl0 + 4) * D_HID + d] = acc1;
    h[(node0 + nl0 + 8) * D_HID + d] = acc2;
    h[(node0 + nl0 + 12) * D_HID + d] = acc3;
}

// --- h_agg init with self-loop term: dinv[n]^2 * h_lin[n] ---
__global__ __launch_bounds__(256) void selfloop_kernel(const float* __restrict__ h_lin,
                                                       const float* __restrict__ dinv,
                                                       float* __restrict__ h_agg) {
    int i = blockIdx.x * 256 + threadIdx.x;   // over N_NODES*64
    int n = i >> 6;
    float di = dinv[n];
    h_agg[i] = h_lin[i] * (di * di);
}

// --- scatter: wave per edge, lane = feature; atomicAdd into h_agg[col] ---
__global__ __launch_bounds__(256) void scatter_kernel(const float* __restrict__ h_lin,
                                                      const float* __restrict__ dinv,
                                                      const int* __restrict__ row,
                                                      const int* __restrict__ col,
                                                      float* __restrict__ h_agg) {
    int i = blockIdx.x * 256 + threadIdx.x;   // over N_EDGES*64 = 102.4M (< 2^31)
    int e = i >> 6;
    int d = i & 63;
    int r = row[e], c = col[e];               // wave-uniform loads
    float norm = dinv[r] * dinv[c];
    atomicAdd(&h_agg[c * 64 + d], h_lin[r * 64 + d] * norm);
}

// --- epilogue: +b1, relu, BN(eval), relu — in place ---
__global__ __launch_bounds__(256) void post_kernel(float* __restrict__ h,
                                                   const float* __restrict__ b1,
                                                   const float* __restrict__ gamma,
                                                   const float* __restrict__ beta,
                                                   const float* __restrict__ mean,
                                                   const float* __restrict__ var) {
    int i = blockIdx.x * 256 + threadIdx.x;   // over N_NODES*64
    int d = i & 63;
    float v = h[i] + b1[d];
    v = fmaxf(v, 0.f);
    v = (v - mean[d]) * rsqrtf(var[d] + BN_EPS) * gamma[d] + beta[d];
    h[i] = fmaxf(v, 0.f);
}

// --- edge head: wave per edge, lane d covers feature d of both endpoints ---
__global__ __launch_bounds__(256) void edgeout_kernel(const float* __restrict__ h,
                                                      const int* __restrict__ row,
                                                      const int* __restrict__ col,
                                                      const float* __restrict__ Wfc,
                                                      const float* __restrict__ bfc,
                                                      float* __restrict__ out) {
    int i = blockIdx.x * 256 + threadIdx.x;   // over N_EDGES*64
    int e = i >> 6;
    int d = i & 63;
    int r = row[e], c = col[e];
    float hr = h[r * 64 + d];
    float hc = h[c * 64 + d];
    float p0 = hr * Wfc[2 * d]     + hc * Wfc[2 * (64 + d)];
    float p1 = hr * Wfc[2 * d + 1] + hc * Wfc[2 * (64 + d) + 1];
    #pragma unroll
    for (int off = 32; off > 0; off >>= 1) {
        p0 += __shfl_down(p0, off, 64);
        p1 += __shfl_down(p1, off, 64);
    }
    if (d == 0) {
        out[e * 2]     = p0 + bfc[0];
        out[e * 2 + 1] = p1 + bfc[1];
    }
}

extern "C" void kernel_launch(void* const* d_in, const int* in_sizes, int n_in,
                              void* d_out, int out_size, void* d_ws, size_t ws_size,
                              hipStream_t stream) {
    const float* x     = (const float*)d_in[0];
    const int*   ei    = (const int*)d_in[1];
    const int*   row   = ei;             // edge_index[0] = sources
    const int*   col   = ei + N_EDGES;   // edge_index[1] = targets
    const float* W1    = (const float*)d_in[2];
    const float* b1    = (const float*)d_in[3];
    const float* gamma = (const float*)d_in[4];
    const float* beta  = (const float*)d_in[5];
    const float* mean  = (const float*)d_in[6];
    const float* var   = (const float*)d_in[7];
    const float* Wfc   = (const float*)d_in[8];
    const float* bfc   = (const float*)d_in[9];
    float* out = (float*)d_out;

    char* ws = (char*)d_ws;
    float* deg   = (float*)ws;                               // 400 KB
    float* h_lin = (float*)(ws + (size_t)N_NODES * 4);       // 25.6 MB
    float* h_agg = h_lin + (size_t)N_NODES * D_HID;          // 25.6 MB

    hipMemsetAsync(deg, 0, N_NODES * sizeof(float), stream);
    deg_kernel<<<(N_EDGES + 255) / 256, 256, 0, stream>>>(col, deg);
    dinv_kernel<<<(N_NODES + 255) / 256, 256, 0, stream>>>(deg);
    gemm_kernel<<<N_NODES / 16, 256, 0, stream>>>(x, W1, h_lin);
    selfloop_kernel<<<(N_NODES * 64) / 256, 256, 0, stream>>>(h_lin, deg, h_agg);
    scatter_kernel<<<(N_EDGES * 64) / 256, 256, 0, stream>>>(h_lin, deg, row, col, h_agg);
    post_kernel<<<(N_NODES * 64) / 256, 256, 0, stream>>>(h_agg, b1, gamma, beta, mean, var);
    edgeout_kernel<<<(N_EDGES * 64) / 256, 256, 0, stream>>>(h_agg, row, col, Wfc, bfc, out);
}

// Round 2
// 434.637 us; speedup vs baseline: 1.9529x; 1.9529x over previous
//
#include <hip/hip_runtime.h>

#define N_NODES 100000
#define N_EDGES 1600000
#define D_IN 128
#define D_HID 64
#define BN_EPS 1e-5f
#define SCAN_BLK 1024
#define N_SCAN_BLKS ((N_NODES + SCAN_BLK - 1) / SCAN_BLK)   // 98

// --- degree count (int): one thread per edge ---
__global__ __launch_bounds__(256) void deg_kernel(const int* __restrict__ col,
                                                  int* __restrict__ deg) {
    int e = blockIdx.x * 256 + threadIdx.x;
    if (e < N_EDGES) atomicAdd(&deg[col[e]], 1);
}

// --- dinv = rsqrt(deg + 1)  (self-loop) ---
__global__ __launch_bounds__(256) void dinv_kernel(const int* __restrict__ deg,
                                                   float* __restrict__ dinv) {
    int n = blockIdx.x * 256 + threadIdx.x;
    if (n < N_NODES) dinv[n] = rsqrtf((float)deg[n] + 1.0f);
}

// --- scan pass 1: per-block exclusive scan of deg, block totals out ---
__global__ __launch_bounds__(SCAN_BLK) void scan1_kernel(const int* __restrict__ deg,
                                                         int* __restrict__ row_start,
                                                         int* __restrict__ bsum) {
    __shared__ int tmp[SCAN_BLK];
    int i = blockIdx.x * SCAN_BLK + threadIdx.x;
    int t = threadIdx.x;
    int val = (i < N_NODES) ? deg[i] : 0;
    tmp[t] = val;
    for (int off = 1; off < SCAN_BLK; off <<= 1) {
        __syncthreads();
        int add = (t >= off) ? tmp[t - off] : 0;
        __syncthreads();
        tmp[t] += add;
    }
    __syncthreads();
    if (i < N_NODES) row_start[i] = tmp[t] - val;   // exclusive within block
    if (t == SCAN_BLK - 1) bsum[blockIdx.x] = tmp[t];
}

// --- scan pass 2: exclusive scan of the block sums (single block) ---
__global__ __launch_bounds__(128) void scan2_kernel(int* __restrict__ bsum) {
    __shared__ int tmp[128];
    int t = threadIdx.x;
    int val = (t < N_SCAN_BLKS) ? bsum[t] : 0;
    tmp[t] = val;
    for (int off = 1; off < 128; off <<= 1) {
        __syncthreads();
        int add = (t >= off) ? tmp[t - off] : 0;
        __syncthreads();
        tmp[t] += add;
    }
    __syncthreads();
    if (t < N_SCAN_BLKS) bsum[t] = tmp[t] - val;    // exclusive
}

// --- scan pass 3: add block offsets; init cursor ---
__global__ __launch_bounds__(256) void scan3_kernel(int* __restrict__ row_start,
                                                    const int* __restrict__ bsum,
                                                    int* __restrict__ cursor) {
    int i = blockIdx.x * 256 + threadIdx.x;
    if (i < N_NODES) {
        int s = row_start[i] + bsum[i >> 10];
        row_start[i] = s;
        cursor[i] = s;
    }
}

// --- CSR fill: csr_src[slot of col] = row ---
__global__ __launch_bounds__(256) void csrfill_kernel(const int* __restrict__ row,
                                                      const int* __restrict__ col,
                                                      int* __restrict__ cursor,
                                                      int* __restrict__ csr_src) {
    int e = blockIdx.x * 256 + threadIdx.x;
    if (e < N_EDGES) {
        int p = atomicAdd(&cursor[col[e]], 1);
        csr_src[p] = row[e];
    }
}

// --- h_s = dinv[n] * (x @ W1) : 16 nodes per block, W1 + x-tile in LDS ---
__global__ __launch_bounds__(256) void gemm_kernel(const float* __restrict__ x,
                                                   const float* __restrict__ W,
                                                   const float* __restrict__ dinv,
                                                   float* __restrict__ h_s) {
    __shared__ float ws[D_IN * D_HID];   // 32 KB
    __shared__ float xs[16][D_IN];       // 8 KB
    const int t = threadIdx.x;
    for (int i = t; i < D_IN * D_HID; i += 256) ws[i] = W[i];
    const int node0 = blockIdx.x * 16;
    for (int i = t; i < 16 * D_IN; i += 256) {
        int nl = i >> 7, k = i & 127;
        xs[nl][k] = x[(node0 + nl) * D_IN + k];
    }
    __syncthreads();
    const int d = t & 63;
    const int nl0 = t >> 6;      // 0..3
    float acc0 = 0.f, acc1 = 0.f, acc2 = 0.f, acc3 = 0.f;
    for (int k = 0; k < D_IN; ++k) {
        float w = ws[k * D_HID + d];
        acc0 += xs[nl0][k] * w;
        acc1 += xs[nl0 + 4][k] * w;
        acc2 += xs[nl0 + 8][k] * w;
        acc3 += xs[nl0 + 12][k] * w;
    }
    h_s[(node0 + nl0) * D_HID + d]      = acc0 * dinv[node0 + nl0];
    h_s[(node0 + nl0 + 4) * D_HID + d]  = acc1 * dinv[node0 + nl0 + 4];
    h_s[(node0 + nl0 + 8) * D_HID + d]  = acc2 * dinv[node0 + nl0 + 8];
    h_s[(node0 + nl0 + 12) * D_HID + d] = acc3 * dinv[node0 + nl0 + 12];
}

// --- fused aggregate + bias/BN/relu + per-node fc projection ---
// one wave per node; lane = feature d
__global__ __launch_bounds__(256) void aggregate_kernel(const float* __restrict__ h_s,
                                                        const float* __restrict__ dinv,
                                                        const int* __restrict__ row_start,
                                                        const int* __restrict__ deg,
                                                        const int* __restrict__ csr_src,
                                                        const float* __restrict__ b1,
                                                        const float* __restrict__ gamma,
                                                        const float* __restrict__ beta,
                                                        const float* __restrict__ mean,
                                                        const float* __restrict__ var,
                                                        const float* __restrict__ Wfc,
                                                        float4* __restrict__ uv) {
    int n = (blockIdx.x * 256 + threadIdx.x) >> 6;   // node (grid exact)
    int d = threadIdx.x & 63;
    float acc = h_s[n * 64 + d];                     // self-loop term (pre-scaled)
    int start = row_start[n];
    int cnt = deg[n];
    int j = 0;
    for (; j + 4 <= cnt; j += 4) {                   // unrolled for load ILP
        int r0 = csr_src[start + j];
        int r1 = csr_src[start + j + 1];
        int r2 = csr_src[start + j + 2];
        int r3 = csr_src[start + j + 3];
        float a0 = h_s[r0 * 64 + d];
        float a1 = h_s[r1 * 64 + d];
        float a2 = h_s[r2 * 64 + d];
        float a3 = h_s[r3 * 64 + d];
        acc += a0; acc += a1; acc += a2; acc += a3;
    }
    for (; j < cnt; ++j) acc += h_s[csr_src[start + j] * 64 + d];
    float tot = dinv[n] * acc;
    // epilogue: +b1, relu, BN(eval), relu
    float v = fmaxf(tot + b1[d], 0.f);
    v = fmaxf((v - mean[d]) * rsqrtf(var[d] + BN_EPS) * gamma[d] + beta[d], 0.f);
    // project: u = h2·Wfc[0:64,:], v-part = h2·Wfc[64:128,:]
    float p0 = v * Wfc[2 * d];
    float p1 = v * Wfc[2 * d + 1];
    float p2 = v * Wfc[2 * (64 + d)];
    float p3 = v * Wfc[2 * (64 + d) + 1];
    #pragma unroll
    for (int off = 32; off > 0; off >>= 1) {
        p0 += __shfl_down(p0, off, 64);
        p1 += __shfl_down(p1, off, 64);
        p2 += __shfl_down(p2, off, 64);
        p3 += __shfl_down(p3, off, 64);
    }
    if (d == 0) uv[n] = make_float4(p0, p1, p2, p3);
}

// --- edge head: out[e] = uv[row].xy + uv[col].zw + bfc ---
__global__ __launch_bounds__(256) void edgeout_kernel(const int* __restrict__ row,
                                                      const int* __restrict__ col,
                                                      const float4* __restrict__ uv,
                                                      const float* __restrict__ bfc,
                                                      float2* __restrict__ out) {
    int e = blockIdx.x * 256 + threadIdx.x;
    if (e < N_EDGES) {
        float4 a = uv[row[e]];
        float4 b = uv[col[e]];
        out[e] = make_float2(a.x + b.z + bfc[0], a.y + b.w + bfc[1]);
    }
}

extern "C" void kernel_launch(void* const* d_in, const int* in_sizes, int n_in,
                              void* d_out, int out_size, void* d_ws, size_t ws_size,
                              hipStream_t stream) {
    const float* x     = (const float*)d_in[0];
    const int*   ei    = (const int*)d_in[1];
    const int*   row   = ei;             // sources
    const int*   col   = ei + N_EDGES;   // targets
    const float* W1    = (const float*)d_in[2];
    const float* b1    = (const float*)d_in[3];
    const float* gamma = (const float*)d_in[4];
    const float* beta  = (const float*)d_in[5];
    const float* mean  = (const float*)d_in[6];
    const float* var   = (const float*)d_in[7];
    const float* Wfc   = (const float*)d_in[8];
    const float* bfc   = (const float*)d_in[9];
    float2* out = (float2*)d_out;

    char* ws = (char*)d_ws;
    size_t off = 0;
    float* h_s      = (float*)(ws + off); off += (size_t)N_NODES * D_HID * 4;  // 25.6 MB
    int*   csr_src  = (int*)(ws + off);   off += (size_t)N_EDGES * 4;          // 6.4 MB
    int*   deg      = (int*)(ws + off);   off += (size_t)N_NODES * 4;
    int*   rstart   = (int*)(ws + off);   off += (size_t)N_NODES * 4;
    int*   cursor   = (int*)(ws + off);   off += (size_t)N_NODES * 4;
    float* dinv     = (float*)(ws + off); off += (size_t)N_NODES * 4;
    float4* uv      = (float4*)(ws + off); off += (size_t)N_NODES * 16;        // 1.6 MB
    int*   bsum     = (int*)(ws + off);   off += 512;

    hipMemsetAsync(deg, 0, N_NODES * sizeof(int), stream);
    deg_kernel<<<(N_EDGES + 255) / 256, 256, 0, stream>>>(col, deg);
    dinv_kernel<<<(N_NODES + 255) / 256, 256, 0, stream>>>(deg, dinv);
    scan1_kernel<<<N_SCAN_BLKS, SCAN_BLK, 0, stream>>>(deg, rstart, bsum);
    scan2_kernel<<<1, 128, 0, stream>>>(bsum);
    scan3_kernel<<<(N_NODES + 255) / 256, 256, 0, stream>>>(rstart, bsum, cursor);
    csrfill_kernel<<<(N_EDGES + 255) / 256, 256, 0, stream>>>(row, col, cursor, csr_src);
    gemm_kernel<<<N_NODES / 16, 256, 0, stream>>>(x, W1, dinv, h_s);
    aggregate_kernel<<<(N_NODES * 64) / 256, 256, 0, stream>>>(h_s, dinv, rstart, deg,
                                                               csr_src, b1, gamma, beta,
                                                               mean, var, Wfc, uv);
    edgeout_kernel<<<(N_EDGES + 255) / 256, 256, 0, stream>>>(row, col, uv, bfc, out);
}